// Round 1
// 286.743 us; speedup vs baseline: 1.0379x; 1.0379x over previous
//
#include <hip/hip_runtime.h>
#include <hip/hip_bf16.h>

typedef __bf16 bf16x8 __attribute__((ext_vector_type(8)));
typedef __bf16 bf16x4 __attribute__((ext_vector_type(4)));
typedef float  f32x4  __attribute__((ext_vector_type(4)));

#define B_SZ    1024
#define COUT_SZ 512
#define K_SZ    32768   // G * CIN
#define TM 128
#define TN 128
#define BK 32
#define APITCH 36       // A-LDS row pitch in bf16 (72 B): write & b64 frag reads
                        // both land at bank-depth <=2 (verified layout, kept)
#define WPAN (COUT_SZ * BK)   // 16384 elems: one k-panel of k-blocked wt

// async 16B/lane global -> LDS DMA; lane l lands at base + 16*l.
__device__ __forceinline__ void async_copy16(const void* g, void* l) {
  __builtin_amdgcn_global_load_lds(
      (const __attribute__((address_space(1))) unsigned int*)g,
      (__attribute__((address_space(3))) unsigned int*)l, 16, 0, 0);
}

// raw s_barrier with compiler memory fences (NO vmcnt(0) drain - that drain
// is the whole point of this rewrite). sched_barrier pins machine scheduling,
// empty asm-with-memory-clobber pins IR-level movement of LDS ops.
__device__ __forceinline__ void block_barrier() {
  __builtin_amdgcn_sched_barrier(0);
  asm volatile("" ::: "memory");
  __builtin_amdgcn_s_barrier();
  asm volatile("" ::: "memory");
  __builtin_amdgcn_sched_barrier(0);
}

// ---------------------------------------------------------------------------
// W fp32 [k][o] -> wt bf16, K-BLOCKED layout: wt[(k>>5)*WPAN + o*32 + (k&31)].
// One (o, 32k) row = 64 B contiguous; a gemm B-tile (128 o x 32 k) is one
// contiguous 8 KB region -> perfectly coalesced global_load_lds.
// 64x64 tiles via fp32 LDS pitch 65 (<=2-way banks both phases).
// Store phase now writes bf16x8 (16 B/lane, was 8 B).
// ---------------------------------------------------------------------------
__global__ __launch_bounds__(256) void wtrans_kernel(
    const float* __restrict__ w, __bf16* __restrict__ wt) {
  __shared__ float t[64 * 65];
  const int kb = (blockIdx.x & 511) * 64;   // K_SZ/64 = 512
  const int ob = (blockIdx.x >> 9) * 64;
  const int tid = threadIdx.x;
  {  // load 64x64 fp32 tile, coalesced 256B rows
    const int o4 = (tid & 15) * 4;
    const int kr = tid >> 4;
    const float* src = w + (size_t)(kb + kr) * COUT_SZ + ob + o4;
#pragma unroll
    for (int i = 0; i < 4; ++i) {
      f32x4 v = *(const f32x4*)(src + (size_t)(16 * i) * COUT_SZ);
      *(f32x4*)&t[(kr + 16 * i) * 65 + o4] = v;
    }
  }
  __syncthreads();
  {  // transposed gather: bank = (k8+e+o)%32 -> 2-way across the wave (free)
    const int orow = tid >> 3;          // 0..31
    const int k8   = (tid & 7) * 8;     // 0,8,...,56
#pragma unroll
    for (int j = 0; j < 2; ++j) {
      const int o = orow + 32 * j;
      bf16x8 pk;
#pragma unroll
      for (int e = 0; e < 8; ++e) pk[e] = (__bf16)t[(k8 + e) * 65 + o];
      *(bf16x8*)(wt + (size_t)((kb + k8) >> 5) * WPAN
                 + (size_t)(ob + o) * BK + (k8 & 31)) = pk;
    }
  }
}

// ---------------------------------------------------------------------------
// Split-K GEMM, PIPELINED: double-buffered LDS (As 2x9KB, Bs 2x8KB = 34 KB,
// keeps 4 blocks/CU), iteration t+1's A-loads (to regs) and B-DMAs (to the
// other buffer) issue BEFORE the wait; raw s_barrier + counted
// s_waitcnt vmcnt(6) keeps the 6 prefetch ops in flight across the barrier
// (old version: __syncthreads -> vmcnt(0) drain = full HBM latency exposed
// every iter -> MfmaUtil 13%, HBM 35%).
//
// Steady-state iter t:
//   cvt+ds_write A(t) regs -> As[cur]        (lgkm)
//   load A(t+1) -> regs; DMA B(t+1) -> Bs[nxt]
//   s_waitcnt vmcnt(6) lgkmcnt(0)            (B(t) landed, A writes done;
//                                             6 newest ops stay in flight)
//   s_barrier                                (bar4: tiles valid)
//   frag reads from [cur]; 16x MFMA
//   s_barrier                                (bar7: reads done -> buffer
//                                             may be restaged at t+1)
// Hazards: buffer written at t+1 is the one read at t-1; bar7(t) orders it.
// A-writes are cross-wave -> covered by lgkmcnt(0)+bar4.
//
// Block map lin = z + S*t: XCD = z%8; all 32 out-tiles of a z-chunk share one
// XCD's L2. Grid 1024 = fully co-resident at 4 blocks/CU.
// ---------------------------------------------------------------------------
__global__ __launch_bounds__(256, 4)
void gemm_kernel(const float* __restrict__ x, const __bf16* __restrict__ wt,
                 __bf16* __restrict__ dst, int kchunk, int S) {
  __shared__ __bf16 As[2][TM * APITCH];
  __shared__ __bf16 Bs[2][TN * BK];

  const int lin = blockIdx.x;
  const int z = lin % S;
  const int t = lin / S;
  const int m0 = (t & 7) * TM;   // 8 m-tiles
  const int n0 = (t >> 3) * TN;  // 4 n-tiles
  const int tid  = threadIdx.x;
  const int w    = tid >> 6;
  const int lane = tid & 63;
  const int kbase = z * kchunk;

  // A staging geometry: thread -> row tid>>1, k-half (tid&1)*16, fp32 from x
  const int ar = tid >> 1;
  const int ah = tid & 1;
  const float* ag = x + (size_t)(m0 + ar) * K_SZ + kbase + ah * 16;
  const int awOff = ar * APITCH + ah * 16;

  // B staging via DMA from k-blocked wt: wave w stages rows [32w, 32w+32);
  // lane l -> row l>>2, phys chunk l&3 holds logical chunk (l&3)^(row&3).
  // Source region per DMA is 1 KB CONTIGUOUS (swizzle is a permutation of it).
  const int sRow = lane >> 2;
  const int sCh  = (lane & 3) ^ (sRow & 3);
  const __bf16* bg0 = wt + (size_t)(kbase >> 5) * WPAN
                    + (size_t)(n0 + w * 32 + sRow) * BK + sCh * 8;
  const __bf16* bg1 = bg0 + 16 * BK;
  const int bL0 = (w * 32) * BK;
  const int bL1 = bL0 + 16 * BK;

  // fragment geometry
  const int lm = lane & 15;
  const int q  = lane >> 4;
  const int wm = (w & 1) * 64;
  const int wn = (w >> 1) * 64;
  const int pc = q ^ (lm & 3);  // B chunk swizzle at read

  f32x4 acc[4][4];
#pragma unroll
  for (int i = 0; i < 4; ++i)
#pragma unroll
    for (int j = 0; j < 4; ++j)
      acc[i][j] = (f32x4){0.f, 0.f, 0.f, 0.f};

  // prologue: A(0) -> regs, B(0) -> Bs[0] (latency exposed once per block)
  f32x4 pa0 = *(const f32x4*)(ag);
  f32x4 pa1 = *(const f32x4*)(ag + 4);
  f32x4 pa2 = *(const f32x4*)(ag + 8);
  f32x4 pa3 = *(const f32x4*)(ag + 12);
  ag += BK;
  async_copy16(bg0, &Bs[0][bL0]);
  async_copy16(bg1, &Bs[0][bL1]);
  bg0 += WPAN; bg1 += WPAN;

  const int niter = kchunk / BK;
  for (int it = 0; it < niter; ++it) {
    const int cur = it & 1;
    {  // stage A(it): cvt + 4x ds_write_b64 into As[cur]
      __bf16* aw = &As[cur][awOff];
      bf16x4 c0, c1, c2, c3;
#pragma unroll
      for (int e = 0; e < 4; ++e) {
        c0[e] = (__bf16)pa0[e]; c1[e] = (__bf16)pa1[e];
        c2[e] = (__bf16)pa2[e]; c3[e] = (__bf16)pa3[e];
      }
      *(bf16x4*)(aw)      = c0;
      *(bf16x4*)(aw + 4)  = c1;
      *(bf16x4*)(aw + 8)  = c2;
      *(bf16x4*)(aw + 12) = c3;
    }
    if (it + 1 < niter) {
      // prefetch next tile: 4 A-loads + 2 B-DMAs, kept in flight past barrier
      pa0 = *(const f32x4*)(ag);
      pa1 = *(const f32x4*)(ag + 4);
      pa2 = *(const f32x4*)(ag + 8);
      pa3 = *(const f32x4*)(ag + 12);
      ag += BK;
      const int nxt = cur ^ 1;
      async_copy16(bg0, &Bs[nxt][bL0]);
      async_copy16(bg1, &Bs[nxt][bL1]);
      bg0 += WPAN; bg1 += WPAN;
      // vmcnt(6): the 6 ops just issued may stay outstanding; everything
      // older (= B(it)'s 2 DMAs) must have landed. lgkm: A writes done.
      asm volatile("s_waitcnt vmcnt(6) lgkmcnt(0)" ::: "memory");
    } else {
      asm volatile("s_waitcnt vmcnt(0) lgkmcnt(0)" ::: "memory");
    }
    block_barrier();  // bar4: As[cur]/Bs[cur] valid for all waves

    bf16x8 af[4];
#pragma unroll
    for (int i = 0; i < 4; ++i) {
      const __bf16* arow = &As[cur][(wm + i * 16 + lm) * APITCH + q * 8];
      bf16x4 lo = *(const bf16x4*)arow;
      bf16x4 hi = *(const bf16x4*)(arow + 4);
      bf16x8 a;
#pragma unroll
      for (int e = 0; e < 4; ++e) { a[e] = lo[e]; a[e + 4] = hi[e]; }
      af[i] = a;
    }
    __builtin_amdgcn_s_setprio(1);
#pragma unroll
    for (int j = 0; j < 4; ++j) {
      bf16x8 bfr = *(const bf16x8*)&Bs[cur][(wn + j * 16 + lm) * BK + pc * 8];
#pragma unroll
      for (int i = 0; i < 4; ++i)
        acc[i][j] = __builtin_amdgcn_mfma_f32_16x16x32_bf16(af[i], bfr,
                                                            acc[i][j], 0, 0, 0);
    }
    __builtin_amdgcn_s_setprio(0);
    block_barrier();  // bar7: all reads of [cur] retired (MFMA operand waits
                      // forced them) -> iter it+1 may restage this buffer
  }

  // epilogue -> bf16 partials. C/D layout col=lane&15, row=(lane>>4)*4+reg.
  __bf16* outp = dst + (size_t)z * (B_SZ * COUT_SZ)
               + (size_t)(m0 + wm + q * 4) * COUT_SZ + (n0 + wn + lm);
#pragma unroll
  for (int i = 0; i < 4; ++i) {
#pragma unroll
    for (int r = 0; r < 4; ++r) {
      __bf16* o2 = outp + (size_t)(i * 16 + r) * COUT_SZ;
#pragma unroll
      for (int j = 0; j < 4; ++j)
        o2[j * 16] = (__bf16)acc[i][j][r];
    }
  }
}

// ---------------------------------------------------------------------------
// Reduce S bf16 partial slices (fp32 accumulate) + scale by 1/sqrt(512).
// 512 blocks (was 256 = 1 wave/SIMD, latency-bound), 4 outs/thread,
// unroll 4 for load ILP.
// ---------------------------------------------------------------------------
__global__ __launch_bounds__(256) void reduce_kernel(
    const __bf16* __restrict__ p, float* __restrict__ out, int S, float scale) {
  const size_t i = ((size_t)blockIdx.x * 256 + threadIdx.x) * 4;
  float s0 = 0.f, s1 = 0.f, s2 = 0.f, s3 = 0.f;
#pragma unroll 4
  for (int zz = 0; zz < S; ++zz) {
    bf16x4 v = *(const bf16x4*)(p + (size_t)zz * (B_SZ * COUT_SZ) + i);
    s0 += (float)v[0]; s1 += (float)v[1];
    s2 += (float)v[2]; s3 += (float)v[3];
  }
  f32x4 o = {s0 * scale, s1 * scale, s2 * scale, s3 * scale};
  *(f32x4*)(out + i) = o;
}

extern "C" void kernel_launch(void* const* d_in, const int* in_sizes, int n_in,
                              void* d_out, int out_size, void* d_ws, size_t ws_size,
                              hipStream_t stream) {
  const float* x = (const float*)d_in[0];
  const float* w = (const float*)d_in[1];
  float* out = (float*)d_out;

  const size_t wtB    = (size_t)COUT_SZ * K_SZ * sizeof(__bf16);   // 33.5 MB
  const size_t sliceB = (size_t)B_SZ * COUT_SZ * sizeof(__bf16);   // 1 MB

  __bf16* wt = (__bf16*)d_ws;
  __bf16* partials = (__bf16*)((char*)d_ws + wtB);

  int S = 32;  // grid 1024 = 4 blocks/CU fully co-resident; kchunk 1024
  while (S > 1 && wtB + (size_t)S * sliceB > ws_size) S >>= 1;

  const float scale = 0.04419417382415922f;  // 1/sqrt(512)

  hipLaunchKernelGGL(wtrans_kernel, dim3((K_SZ / 64) * (COUT_SZ / 64)), dim3(256),
                     0, stream, w, wt);
  hipLaunchKernelGGL(gemm_kernel, dim3(32 * S), dim3(256), 0, stream,
                     x, wt, partials, K_SZ / S, S);
  hipLaunchKernelGGL(reduce_kernel, dim3(B_SZ * COUT_SZ / (256 * 4)), dim3(256),
                     0, stream, partials, out, S, scale);
}